// Round 3
// baseline (565.748 us; speedup 1.0000x reference)
//
#include <hip/hip_runtime.h>
#include <math.h>
#include <stdint.h>

typedef __bf16 bf16_t;
typedef __bf16 bf16x8 __attribute__((ext_vector_type(8)));
typedef float f32x4 __attribute__((ext_vector_type(4)));
typedef unsigned short ushort8_t __attribute__((ext_vector_type(8)));
typedef unsigned short ushort4_t __attribute__((ext_vector_type(4)));

#define LOG2E 1.44269504088896340736f

__device__ inline unsigned short f2bf_bits(float f) {
  union { float f; unsigned int u; } v; v.f = f;
  unsigned int u = v.u;
  return (unsigned short)((u + 0x7fffu + ((u >> 16) & 1u)) >> 16);
}

// global -> LDS direct copy, 16B per lane. LDS dest is wave-uniform base
// + lane*16 (HW behavior, m104); global src is per-lane.
__device__ inline void gld_lds16(const void* g, void* l) {
  __builtin_amdgcn_global_load_lds(
      (__attribute__((address_space(1))) void*)(uintptr_t)(g),
      (__attribute__((address_space(3))) void*)(uintptr_t)(l),
      16, 0, 0);
}

// ---------------- cast fp32 -> bf16 (weights) ----------------
__global__ __launch_bounds__(256) void cast_kernel(const float* __restrict__ in,
                                                   unsigned short* __restrict__ out,
                                                   int n) {
  int i = (blockIdx.x * 256 + threadIdx.x) * 4;
  if (i >= n) return;
  float4 f = *reinterpret_cast<const float4*>(in + i);
  ushort4_t o;
  o[0] = f2bf_bits(f.x); o[1] = f2bf_bits(f.y);
  o[2] = f2bf_bits(f.z); o[3] = f2bf_bits(f.w);
  *reinterpret_cast<ushort4_t*>(out + i) = o;
}

// ---------------- LayerNorm (C=1024) + cast to bf16 ----------------
__global__ __launch_bounds__(256) void ln_kernel(const float* __restrict__ x,
                                                 const float* __restrict__ g,
                                                 const float* __restrict__ bta,
                                                 unsigned short* __restrict__ out) {
  const int row = blockIdx.x;
  const int c = threadIdx.x * 4;
  const float4 xv = *reinterpret_cast<const float4*>(x + (size_t)row * 1024 + c);
  float s = xv.x + xv.y + xv.z + xv.w;
  float sq = xv.x * xv.x + xv.y * xv.y + xv.z * xv.z + xv.w * xv.w;
#pragma unroll
  for (int xm = 1; xm < 64; xm <<= 1) {
    s += __shfl_xor(s, xm, 64);
    sq += __shfl_xor(sq, xm, 64);
  }
  __shared__ float sh[8];
  const int wave = threadIdx.x >> 6, lane = threadIdx.x & 63;
  if (lane == 0) { sh[wave] = s; sh[4 + wave] = sq; }
  __syncthreads();
  const float ts = sh[0] + sh[1] + sh[2] + sh[3];
  const float tq = sh[4] + sh[5] + sh[6] + sh[7];
  const float mean = ts * (1.0f / 1024.0f);
  const float var = tq * (1.0f / 1024.0f) - mean * mean;
  const float rstd = rsqrtf(var + 1e-5f);
  const float4 gv = *reinterpret_cast<const float4*>(g + c);
  const float4 bv = *reinterpret_cast<const float4*>(bta + c);
  ushort4_t o;
  o[0] = f2bf_bits((xv.x - mean) * rstd * gv.x + bv.x);
  o[1] = f2bf_bits((xv.y - mean) * rstd * gv.y + bv.y);
  o[2] = f2bf_bits((xv.z - mean) * rstd * gv.z + bv.z);
  o[3] = f2bf_bits((xv.w - mean) * rstd * gv.w + bv.w);
  *reinterpret_cast<ushort4_t*>(out + (size_t)row * 1024 + c) = o;
}

// ---------------- GEMM: out[m][n] = sum_k A[m][k]*W[n][k] + bias[n] ----------
// m97 verified structure: 128x128 tile, BK=32, 4 waves each 64x64,
// 16x16x32 bf16 MFMA, global_load_lds width 16, linear LDS, 2 barriers/K-step.
// EPI: 0 = bias -> bf16 out; 1 = bias + residual -> f32 out; 2 = bias+GELU -> bf16
template <int EPI>
__global__ __launch_bounds__(256) void gemm_bt(const unsigned short* __restrict__ A,
                                               const unsigned short* __restrict__ W,
                                               const float* __restrict__ bias,
                                               const float* __restrict__ res,
                                               unsigned short* __restrict__ outb,
                                               float* __restrict__ outf,
                                               int M, int N, int K) {
  __shared__ unsigned short Asb[128 * 32];
  __shared__ unsigned short Bsb[128 * 32];
  const int tid = threadIdx.x;
  const int wave = tid >> 6;
  const int lane = tid & 63;
  const int m0 = blockIdx.y * 128;
  const int n0 = blockIdx.x * 128;
  const int wm = (wave >> 1) * 64;
  const int wn = (wave & 1) * 64;

  f32x4 acc[4][4];
#pragma unroll
  for (int i = 0; i < 4; ++i)
#pragma unroll
    for (int j = 0; j < 4; ++j) { f32x4 z = {0.f, 0.f, 0.f, 0.f}; acc[i][j] = z; }

  for (int kt = 0; kt < K; kt += 32) {
#pragma unroll
    for (int i = 0; i < 2; ++i) {
      const int off = i * 4096 + wave * 1024 + lane * 16;  // byte pos in 8KB tile
      const int r = off >> 6;                              // 64B per row (BK=32)
      const int ce = (off & 63) >> 1;                      // col element
      gld_lds16(A + (size_t)(m0 + r) * K + kt + ce, &Asb[i * 2048 + wave * 512]);
      gld_lds16(W + (size_t)(n0 + r) * K + kt + ce, &Bsb[i * 2048 + wave * 512]);
    }
    __syncthreads();
    bf16x8 af[4], bfr[4];
#pragma unroll
    for (int mi = 0; mi < 4; ++mi)
      af[mi] = *reinterpret_cast<const bf16x8*>(
          &Asb[(wm + mi * 16 + (lane & 15)) * 32 + (lane >> 4) * 8]);
#pragma unroll
    for (int ni = 0; ni < 4; ++ni)
      bfr[ni] = *reinterpret_cast<const bf16x8*>(
          &Bsb[(wn + ni * 16 + (lane & 15)) * 32 + (lane >> 4) * 8]);
#pragma unroll
    for (int mi = 0; mi < 4; ++mi)
#pragma unroll
      for (int ni = 0; ni < 4; ++ni)
        acc[mi][ni] =
            __builtin_amdgcn_mfma_f32_16x16x32_bf16(af[mi], bfr[ni], acc[mi][ni], 0, 0, 0);
    __syncthreads();
  }

  // epilogue: D row=(lane>>4)*4+reg, col=lane&15 (m89/m91 verified)
#pragma unroll
  for (int ni = 0; ni < 4; ++ni) {
    const int col = n0 + wn + ni * 16 + (lane & 15);
    const float bv = bias[col];
#pragma unroll
    for (int mi = 0; mi < 4; ++mi) {
#pragma unroll
      for (int r = 0; r < 4; ++r) {
        const int row = m0 + wm + mi * 16 + ((lane >> 4) << 2) + r;
        const size_t idx = (size_t)row * N + col;
        const float v = acc[mi][ni][r] + bv;
        if (EPI == 0) {
          outb[idx] = f2bf_bits(v);
        } else if (EPI == 1) {
          outf[idx] = v + res[idx];
        } else {
          const float gl = 0.5f * v * (1.0f + erff(v * 0.70710678118654752f));
          outb[idx] = f2bf_bits(gl);
        }
      }
    }
  }
}

// ---------------- causal flash attention ----------------
// kqv: [B*T][3072] bf16, per head h: k at h*192, q at h*192+64, v at h*192+128
// grid: (T/64, B*H). block: 256 = 4 waves; wave w owns q rows q0+16w..+15.
// LDS rows are 64 elements (128B) -> 16-way bank conflict if linear (G4);
// XOR swizzle elem ^= (row&7)<<3 on all three buffers (+89% in m214).
__device__ inline int swz(int row, int colelem) {
  return row * 64 + (colelem ^ ((row & 7) << 3));
}

__global__ __launch_bounds__(256) void attn_kernel(const unsigned short* __restrict__ kqv,
                                                   unsigned short* __restrict__ y) {
  __shared__ unsigned short Ks[64 * 64];
  __shared__ unsigned short Vt[64 * 64];
  __shared__ unsigned short Ps[4][16 * 64];

  const int tid = threadIdx.x;
  const int wave = tid >> 6;
  const int lane = tid & 63;
  const int qb = blockIdx.x;
  const int bh = blockIdx.y;
  const int b = bh >> 4;
  const int h = bh & 15;
  const int q0 = qb * 64;
  const int hoff = h * 192;

  // Q fragments, pre-scaled by 1/sqrt(64)=0.125 (exact in bf16)
  bf16x8 qf[2];
  {
    const int qrow = q0 + wave * 16 + (lane & 15);
    const unsigned short* qp =
        kqv + (size_t)(b * 1024 + qrow) * 3072 + hoff + 64 + (lane >> 4) * 8;
#pragma unroll
    for (int kk = 0; kk < 2; ++kk) {
      bf16x8 t = *reinterpret_cast<const bf16x8*>(qp + kk * 32);
#pragma unroll
      for (int e = 0; e < 8; ++e) t[e] = (bf16_t)((float)t[e] * 0.125f);
      qf[kk] = t;
    }
  }

  f32x4 acc_o[4];
#pragma unroll
  for (int dt = 0; dt < 4; ++dt) { f32x4 z = {0.f, 0.f, 0.f, 0.f}; acc_o[dt] = z; }
  float mrow[4] = {-1e30f, -1e30f, -1e30f, -1e30f};
  float lrow[4] = {0.f, 0.f, 0.f, 0.f};

  const int ntiles = qb + 1;
  for (int jt = 0; jt < ntiles; ++jt) {
    const int j0 = jt * 64;
    __syncthreads();  // prior PV reads of Ks/Vt done before overwrite
    // stage K tile [64 j][64 d], swizzled via pre-swizzled global source (m173)
#pragma unroll
    for (int i = 0; i < 4; ++i) {
      const int off = i * 4096 + wave * 1024 + lane * 16;  // byte pos in 8KB
      const int jr = off >> 7;
      const int ce = ((off & 127) >> 1) ^ ((jr & 7) << 3);
      gld_lds16(kqv + (size_t)(b * 1024 + j0 + jr) * 3072 + hoff + ce,
                &Ks[i * 2048 + wave * 512]);
    }
    // stage V transposed: Vt[d][j] (reg-staged, swizzled writes)
#pragma unroll
    for (int p = 0; p < 2; ++p) {
      const int id = p * 256 + tid;
      const int j = id & 63;
      const int dg = id >> 6;  // 0..7 over two passes
      const ushort8_t v = *reinterpret_cast<const ushort8_t*>(
          kqv + (size_t)(b * 1024 + j0 + j) * 3072 + hoff + 128 + dg * 8);
#pragma unroll
      for (int e = 0; e < 8; ++e) Vt[swz(dg * 8 + e, j)] = v[e];
    }
    __syncthreads();

    // S = (Q*scale) @ K^T : per wave 16q x 64j
    f32x4 s[4];
#pragma unroll
    for (int nt = 0; nt < 4; ++nt) {
      f32x4 a = {0.f, 0.f, 0.f, 0.f};
#pragma unroll
      for (int kk = 0; kk < 2; ++kk) {
        const bf16x8 kf = *reinterpret_cast<const bf16x8*>(
            &Ks[swz(nt * 16 + (lane & 15), kk * 32 + (lane >> 4) * 8)]);
        a = __builtin_amdgcn_mfma_f32_16x16x32_bf16(qf[kk], kf, a, 0, 0, 0);
      }
      s[nt] = a;
    }

    // causal mask + online softmax (wave-parallel reduce across 16 lanes)
#pragma unroll
    for (int r = 0; r < 4; ++r) {
      const int qg = q0 + wave * 16 + ((lane >> 4) << 2) + r;
      float mx = -1e30f;
#pragma unroll
      for (int nt = 0; nt < 4; ++nt) {
        const int jg = j0 + nt * 16 + (lane & 15);
        const float sv = (jg <= qg) ? s[nt][r] : -1e30f;
        s[nt][r] = sv;
        mx = fmaxf(mx, sv);
      }
#pragma unroll
      for (int xm = 1; xm < 16; xm <<= 1) mx = fmaxf(mx, __shfl_xor(mx, xm, 64));
      const float mnew = fmaxf(mrow[r], mx);
      const float sc = exp2f((mrow[r] - mnew) * LOG2E);
      mrow[r] = mnew;
      float ssum = 0.f;
#pragma unroll
      for (int nt = 0; nt < 4; ++nt) {
        const float p = exp2f((s[nt][r] - mnew) * LOG2E);
        s[nt][r] = p;
        ssum += p;
      }
#pragma unroll
      for (int xm = 1; xm < 16; xm <<= 1) ssum += __shfl_xor(ssum, xm, 64);
      lrow[r] = lrow[r] * sc + ssum;
#pragma unroll
      for (int dt = 0; dt < 4; ++dt) acc_o[dt][r] *= sc;
    }

    // write P (bf16) to per-wave LDS, swizzled
    unsigned short* Pw = &Ps[wave][0];
#pragma unroll
    for (int nt = 0; nt < 4; ++nt)
#pragma unroll
      for (int r = 0; r < 4; ++r)
        Pw[swz(((lane >> 4) << 2) + r, nt * 16 + (lane & 15))] = f2bf_bits(s[nt][r]);
    __syncthreads();

    // O += P @ V : A-frag rows = lane&15 from Ps, B-frag cols d from Vt
#pragma unroll
    for (int kk = 0; kk < 2; ++kk) {
      const bf16x8 pf = *reinterpret_cast<const bf16x8*>(
          &Ps[wave][swz(lane & 15, kk * 32 + (lane >> 4) * 8)]);
#pragma unroll
      for (int dt = 0; dt < 4; ++dt) {
        const bf16x8 vf = *reinterpret_cast<const bf16x8*>(
            &Vt[swz(dt * 16 + (lane & 15), kk * 32 + (lane >> 4) * 8)]);
        acc_o[dt] = __builtin_amdgcn_mfma_f32_16x16x32_bf16(pf, vf, acc_o[dt], 0, 0, 0);
      }
    }
  }

  // y[b,t, h*64 + d] = O / l
#pragma unroll
  for (int dt = 0; dt < 4; ++dt)
#pragma unroll
    for (int r = 0; r < 4; ++r) {
      const int qg = q0 + wave * 16 + ((lane >> 4) << 2) + r;
      const float o = acc_o[dt][r] / lrow[r];
      y[(size_t)(b * 1024 + qg) * 1024 + h * 64 + dt * 16 + (lane & 15)] =
          f2bf_bits(o);
    }
}

// ---------------- launch ----------------
extern "C" void kernel_launch(void* const* d_in, const int* in_sizes, int n_in,
                              void* d_out, int out_size, void* d_ws, size_t ws_size,
                              hipStream_t stream) {
  const float* x = (const float*)d_in[0];
  const float* kqv_w = (const float*)d_in[1];
  const float* kqv_b = (const float*)d_in[2];
  const float* proj_w = (const float*)d_in[3];
  const float* proj_b = (const float*)d_in[4];
  const float* ln1_g = (const float*)d_in[5];
  const float* ln1_b = (const float*)d_in[6];
  const float* ln2_g = (const float*)d_in[7];
  const float* ln2_b = (const float*)d_in[8];
  const float* fc1_w = (const float*)d_in[9];
  const float* fc1_b = (const float*)d_in[10];
  const float* fc2_w = (const float*)d_in[11];
  const float* fc2_b = (const float*)d_in[12];
  float* out = (float*)d_out;

  char* ws = (char*)d_ws;
  size_t off = 0;
  auto alloc = [&](size_t bytes) {
    char* p = ws + off;
    off += (bytes + 255) & ~(size_t)255;
    return p;
  };
  unsigned short* wk = (unsigned short*)alloc((size_t)3072 * 1024 * 2);
  unsigned short* wp = (unsigned short*)alloc((size_t)1024 * 1024 * 2);
  unsigned short* w1 = (unsigned short*)alloc((size_t)4096 * 1024 * 2);
  unsigned short* w2 = (unsigned short*)alloc((size_t)4096 * 1024 * 2);
  unsigned short* hbuf = (unsigned short*)alloc((size_t)8192 * 1024 * 2);  // LN1 out, reused for LN2 out
  unsigned short* kqvb = (unsigned short*)alloc((size_t)8192 * 3072 * 2);
  unsigned short* yb = (unsigned short*)alloc((size_t)8192 * 1024 * 2);
  float* x1 = (float*)alloc((size_t)8192 * 1024 * 4);
  unsigned short* a1 = (unsigned short*)alloc((size_t)8192 * 4096 * 2);

  // cast weights to bf16
  cast_kernel<<<dim3(3072 * 1024 / 1024), 256, 0, stream>>>(kqv_w, wk, 3072 * 1024);
  cast_kernel<<<dim3(1024 * 1024 / 1024), 256, 0, stream>>>(proj_w, wp, 1024 * 1024);
  cast_kernel<<<dim3(4096 * 1024 / 1024), 256, 0, stream>>>(fc1_w, w1, 4096 * 1024);
  cast_kernel<<<dim3(4096 * 1024 / 1024), 256, 0, stream>>>(fc2_w, w2, 4096 * 1024);

  // LN1 -> h (bf16)
  ln_kernel<<<dim3(8192), 256, 0, stream>>>(x, ln1_g, ln1_b, hbuf);

  // kqv = h @ kqv_w^T + b   [8192 x 3072]
  gemm_bt<0><<<dim3(3072 / 128, 8192 / 128), 256, 0, stream>>>(
      hbuf, wk, kqv_b, nullptr, kqvb, nullptr, 8192, 3072, 1024);

  // attention -> y (bf16)
  attn_kernel<<<dim3(16, 128), 256, 0, stream>>>(kqvb, yb);

  // x1 = x + y @ proj_w^T + b   (fp32)
  gemm_bt<1><<<dim3(1024 / 128, 8192 / 128), 256, 0, stream>>>(
      yb, wp, proj_b, x, nullptr, x1, 8192, 1024, 1024);

  // LN2 -> h (bf16, reuse)
  ln_kernel<<<dim3(8192), 256, 0, stream>>>(x1, ln2_g, ln2_b, hbuf);

  // a1 = gelu(h @ fc1_w^T + b)  [8192 x 4096] bf16
  gemm_bt<2><<<dim3(4096 / 128, 8192 / 128), 256, 0, stream>>>(
      hbuf, w1, fc1_b, nullptr, a1, nullptr, 8192, 4096, 1024);

  // out = x1 + a1 @ fc2_w^T + b  (fp32)
  gemm_bt<1><<<dim3(1024 / 128, 8192 / 128), 256, 0, stream>>>(
      a1, w2, fc2_b, x1, nullptr, out, 8192, 1024, 4096);
}

// Round 4
// 564.843 us; speedup vs baseline: 1.0016x; 1.0016x over previous
//
#include <hip/hip_runtime.h>
#include <math.h>
#include <stdint.h>

typedef __bf16 bf16_t;
typedef __bf16 bf16x8 __attribute__((ext_vector_type(8)));
typedef float f32x4 __attribute__((ext_vector_type(4)));
typedef unsigned short ushort8_t __attribute__((ext_vector_type(8)));
typedef unsigned short ushort4_t __attribute__((ext_vector_type(4)));

#define LOG2E 1.44269504088896340736f

__device__ inline unsigned short f2bf_bits(float f) {
  union { float f; unsigned int u; } v; v.f = f;
  unsigned int u = v.u;
  return (unsigned short)((u + 0x7fffu + ((u >> 16) & 1u)) >> 16);
}

// global -> LDS direct copy, 16B per lane. LDS dest is wave-uniform base
// + lane*16 (HW behavior, m104); global src is per-lane.
__device__ inline void gld_lds16(const void* g, void* l) {
  __builtin_amdgcn_global_load_lds(
      (__attribute__((address_space(1))) void*)(uintptr_t)(g),
      (__attribute__((address_space(3))) void*)(uintptr_t)(l),
      16, 0, 0);
}

// ---------------- cast fp32 -> bf16 (weights) ----------------
__global__ __launch_bounds__(256) void cast_kernel(const float* __restrict__ in,
                                                   unsigned short* __restrict__ out,
                                                   int n) {
  int i = (blockIdx.x * 256 + threadIdx.x) * 4;
  if (i >= n) return;
  float4 f = *reinterpret_cast<const float4*>(in + i);
  ushort4_t o;
  o[0] = f2bf_bits(f.x); o[1] = f2bf_bits(f.y);
  o[2] = f2bf_bits(f.z); o[3] = f2bf_bits(f.w);
  *reinterpret_cast<ushort4_t*>(out + i) = o;
}

// ---------------- LayerNorm (C=1024) + cast to bf16 ----------------
__global__ __launch_bounds__(256) void ln_kernel(const float* __restrict__ x,
                                                 const float* __restrict__ g,
                                                 const float* __restrict__ bta,
                                                 unsigned short* __restrict__ out) {
  const int row = blockIdx.x;
  const int c = threadIdx.x * 4;
  const float4 xv = *reinterpret_cast<const float4*>(x + (size_t)row * 1024 + c);
  float s = xv.x + xv.y + xv.z + xv.w;
  float sq = xv.x * xv.x + xv.y * xv.y + xv.z * xv.z + xv.w * xv.w;
#pragma unroll
  for (int xm = 1; xm < 64; xm <<= 1) {
    s += __shfl_xor(s, xm, 64);
    sq += __shfl_xor(sq, xm, 64);
  }
  __shared__ float sh[8];
  const int wave = threadIdx.x >> 6, lane = threadIdx.x & 63;
  if (lane == 0) { sh[wave] = s; sh[4 + wave] = sq; }
  __syncthreads();
  const float ts = sh[0] + sh[1] + sh[2] + sh[3];
  const float tq = sh[4] + sh[5] + sh[6] + sh[7];
  const float mean = ts * (1.0f / 1024.0f);
  const float var = tq * (1.0f / 1024.0f) - mean * mean;
  const float rstd = rsqrtf(var + 1e-5f);
  const float4 gv = *reinterpret_cast<const float4*>(g + c);
  const float4 bv = *reinterpret_cast<const float4*>(bta + c);
  ushort4_t o;
  o[0] = f2bf_bits((xv.x - mean) * rstd * gv.x + bv.x);
  o[1] = f2bf_bits((xv.y - mean) * rstd * gv.y + bv.y);
  o[2] = f2bf_bits((xv.z - mean) * rstd * gv.z + bv.z);
  o[3] = f2bf_bits((xv.w - mean) * rstd * gv.w + bv.w);
  *reinterpret_cast<ushort4_t*>(out + (size_t)row * 1024 + c) = o;
}

// ---------------- GEMM: out[m][n] = sum_k A[m][k]*W[n][k] + bias[n] ----------
// m97 verified structure: 128x128 tile, BK=32, 4 waves each 64x64,
// 16x16x32 bf16 MFMA, global_load_lds width 16, linear LDS, 2 barriers/K-step.
// EPI: 0 = bias -> bf16 out; 1 = bias + residual -> f32 out; 2 = bias+GELU -> bf16
template <int EPI>
__global__ __launch_bounds__(256) void gemm_bt(const unsigned short* __restrict__ A,
                                               const unsigned short* __restrict__ W,
                                               const float* __restrict__ bias,
                                               const float* __restrict__ res,
                                               unsigned short* __restrict__ outb,
                                               float* __restrict__ outf,
                                               int M, int N, int K) {
  __shared__ unsigned short Asb[128 * 32];
  __shared__ unsigned short Bsb[128 * 32];
  const int tid = threadIdx.x;
  const int wave = tid >> 6;
  const int lane = tid & 63;
  const int m0 = blockIdx.y * 128;
  const int n0 = blockIdx.x * 128;
  const int wm = (wave >> 1) * 64;
  const int wn = (wave & 1) * 64;

  f32x4 acc[4][4];
#pragma unroll
  for (int i = 0; i < 4; ++i)
#pragma unroll
    for (int j = 0; j < 4; ++j) { f32x4 z = {0.f, 0.f, 0.f, 0.f}; acc[i][j] = z; }

  for (int kt = 0; kt < K; kt += 32) {
#pragma unroll
    for (int i = 0; i < 2; ++i) {
      const int off = i * 4096 + wave * 1024 + lane * 16;  // byte pos in 8KB tile
      const int r = off >> 6;                              // 64B per row (BK=32)
      const int ce = (off & 63) >> 1;                      // col element
      gld_lds16(A + (size_t)(m0 + r) * K + kt + ce, &Asb[i * 2048 + wave * 512]);
      gld_lds16(W + (size_t)(n0 + r) * K + kt + ce, &Bsb[i * 2048 + wave * 512]);
    }
    __syncthreads();
    bf16x8 af[4], bfr[4];
#pragma unroll
    for (int mi = 0; mi < 4; ++mi)
      af[mi] = *reinterpret_cast<const bf16x8*>(
          &Asb[(wm + mi * 16 + (lane & 15)) * 32 + (lane >> 4) * 8]);
#pragma unroll
    for (int ni = 0; ni < 4; ++ni)
      bfr[ni] = *reinterpret_cast<const bf16x8*>(
          &Bsb[(wn + ni * 16 + (lane & 15)) * 32 + (lane >> 4) * 8]);
#pragma unroll
    for (int mi = 0; mi < 4; ++mi)
#pragma unroll
      for (int ni = 0; ni < 4; ++ni)
        acc[mi][ni] =
            __builtin_amdgcn_mfma_f32_16x16x32_bf16(af[mi], bfr[ni], acc[mi][ni], 0, 0, 0);
    __syncthreads();
  }

  // epilogue: D row=(lane>>4)*4+reg, col=lane&15 (m89/m91 verified)
#pragma unroll
  for (int ni = 0; ni < 4; ++ni) {
    const int col = n0 + wn + ni * 16 + (lane & 15);
    const float bv = bias[col];
#pragma unroll
    for (int mi = 0; mi < 4; ++mi) {
#pragma unroll
      for (int r = 0; r < 4; ++r) {
        const int row = m0 + wm + mi * 16 + ((lane >> 4) << 2) + r;
        const size_t idx = (size_t)row * N + col;
        const float v = acc[mi][ni][r] + bv;
        if (EPI == 0) {
          outb[idx] = f2bf_bits(v);
        } else if (EPI == 1) {
          outf[idx] = v + res[idx];
        } else {
          const float gl = 0.5f * v * (1.0f + erff(v * 0.70710678118654752f));
          outb[idx] = f2bf_bits(gl);
        }
      }
    }
  }
}

// ---------------- causal flash attention ----------------
// kqv: [B*T][3072] bf16, per head h: k at h*192, q at h*192+64, v at h*192+128
// grid: (T/64, B*H). block: 256 = 4 waves; wave w owns q rows q0+16w..+15.
// LDS rows are 64 elements (128B) -> 16-way bank conflict if linear (G4);
// XOR swizzle elem ^= (row&7)<<3 on all three buffers (+89% in m214).
__device__ inline int swz(int row, int colelem) {
  return row * 64 + (colelem ^ ((row & 7) << 3));
}

__global__ __launch_bounds__(256) void attn_kernel(const unsigned short* __restrict__ kqv,
                                                   unsigned short* __restrict__ y) {
  __shared__ unsigned short Ks[64 * 64];
  __shared__ unsigned short Vt[64 * 64];
  __shared__ unsigned short Ps[4][16 * 64];

  const int tid = threadIdx.x;
  const int wave = tid >> 6;
  const int lane = tid & 63;
  const int qb = blockIdx.x;
  const int bh = blockIdx.y;
  const int b = bh >> 4;
  const int h = bh & 15;
  const int q0 = qb * 64;
  const int hoff = h * 192;

  // Q fragments, pre-scaled by 1/sqrt(64)=0.125 (exact in bf16)
  bf16x8 qf[2];
  {
    const int qrow = q0 + wave * 16 + (lane & 15);
    const unsigned short* qp =
        kqv + (size_t)(b * 1024 + qrow) * 3072 + hoff + 64 + (lane >> 4) * 8;
#pragma unroll
    for (int kk = 0; kk < 2; ++kk) {
      bf16x8 t = *reinterpret_cast<const bf16x8*>(qp + kk * 32);
#pragma unroll
      for (int e = 0; e < 8; ++e) t[e] = (bf16_t)((float)t[e] * 0.125f);
      qf[kk] = t;
    }
  }

  f32x4 acc_o[4];
#pragma unroll
  for (int dt = 0; dt < 4; ++dt) { f32x4 z = {0.f, 0.f, 0.f, 0.f}; acc_o[dt] = z; }
  float mrow[4] = {-1e30f, -1e30f, -1e30f, -1e30f};
  float lrow[4] = {0.f, 0.f, 0.f, 0.f};

  const int ntiles = qb + 1;
  for (int jt = 0; jt < ntiles; ++jt) {
    const int j0 = jt * 64;
    __syncthreads();  // prior PV reads of Ks/Vt done before overwrite
    // stage K tile [64 j][64 d], swizzled via pre-swizzled global source (m173)
#pragma unroll
    for (int i = 0; i < 4; ++i) {
      const int off = i * 4096 + wave * 1024 + lane * 16;  // byte pos in 8KB
      const int jr = off >> 7;
      const int ce = ((off & 127) >> 1) ^ ((jr & 7) << 3);
      gld_lds16(kqv + (size_t)(b * 1024 + j0 + jr) * 3072 + hoff + ce,
                &Ks[i * 2048 + wave * 512]);
    }
    // stage V transposed: Vt[d][j] (reg-staged, swizzled writes)
#pragma unroll
    for (int p = 0; p < 2; ++p) {
      const int id = p * 256 + tid;
      const int j = id & 63;
      const int dg = id >> 6;  // 0..7 over two passes
      const ushort8_t v = *reinterpret_cast<const ushort8_t*>(
          kqv + (size_t)(b * 1024 + j0 + j) * 3072 + hoff + 128 + dg * 8);
#pragma unroll
      for (int e = 0; e < 8; ++e) Vt[swz(dg * 8 + e, j)] = v[e];
    }
    __syncthreads();

    // S = (Q*scale) @ K^T : per wave 16q x 64j
    f32x4 s[4];
#pragma unroll
    for (int nt = 0; nt < 4; ++nt) {
      f32x4 a = {0.f, 0.f, 0.f, 0.f};
#pragma unroll
      for (int kk = 0; kk < 2; ++kk) {
        const bf16x8 kf = *reinterpret_cast<const bf16x8*>(
            &Ks[swz(nt * 16 + (lane & 15), kk * 32 + (lane >> 4) * 8)]);
        a = __builtin_amdgcn_mfma_f32_16x16x32_bf16(qf[kk], kf, a, 0, 0, 0);
      }
      s[nt] = a;
    }

    // causal mask + online softmax (wave-parallel reduce across 16 lanes)
#pragma unroll
    for (int r = 0; r < 4; ++r) {
      const int qg = q0 + wave * 16 + ((lane >> 4) << 2) + r;
      float mx = -1e30f;
#pragma unroll
      for (int nt = 0; nt < 4; ++nt) {
        const int jg = j0 + nt * 16 + (lane & 15);
        const float sv = (jg <= qg) ? s[nt][r] : -1e30f;
        s[nt][r] = sv;
        mx = fmaxf(mx, sv);
      }
#pragma unroll
      for (int xm = 1; xm < 16; xm <<= 1) mx = fmaxf(mx, __shfl_xor(mx, xm, 64));
      const float mnew = fmaxf(mrow[r], mx);
      const float sc = exp2f((mrow[r] - mnew) * LOG2E);
      mrow[r] = mnew;
      float ssum = 0.f;
#pragma unroll
      for (int nt = 0; nt < 4; ++nt) {
        const float p = exp2f((s[nt][r] - mnew) * LOG2E);
        s[nt][r] = p;
        ssum += p;
      }
#pragma unroll
      for (int xm = 1; xm < 16; xm <<= 1) ssum += __shfl_xor(ssum, xm, 64);
      lrow[r] = lrow[r] * sc + ssum;
#pragma unroll
      for (int dt = 0; dt < 4; ++dt) acc_o[dt][r] *= sc;
    }

    // write P (bf16) to per-wave LDS, swizzled
    unsigned short* Pw = &Ps[wave][0];
#pragma unroll
    for (int nt = 0; nt < 4; ++nt)
#pragma unroll
      for (int r = 0; r < 4; ++r)
        Pw[swz(((lane >> 4) << 2) + r, nt * 16 + (lane & 15))] = f2bf_bits(s[nt][r]);
    __syncthreads();

    // O += P @ V : A-frag rows = lane&15 from Ps, B-frag cols d from Vt
#pragma unroll
    for (int kk = 0; kk < 2; ++kk) {
      const bf16x8 pf = *reinterpret_cast<const bf16x8*>(
          &Ps[wave][swz(lane & 15, kk * 32 + (lane >> 4) * 8)]);
#pragma unroll
      for (int dt = 0; dt < 4; ++dt) {
        const bf16x8 vf = *reinterpret_cast<const bf16x8*>(
            &Vt[swz(dt * 16 + (lane & 15), kk * 32 + (lane >> 4) * 8)]);
        acc_o[dt] = __builtin_amdgcn_mfma_f32_16x16x32_bf16(pf, vf, acc_o[dt], 0, 0, 0);
      }
    }
  }

  // y[b,t, h*64 + d] = O / l
#pragma unroll
  for (int dt = 0; dt < 4; ++dt)
#pragma unroll
    for (int r = 0; r < 4; ++r) {
      const int qg = q0 + wave * 16 + ((lane >> 4) << 2) + r;
      const float o = acc_o[dt][r] / lrow[r];
      y[(size_t)(b * 1024 + qg) * 1024 + h * 64 + dt * 16 + (lane & 15)] =
          f2bf_bits(o);
    }
}

// ---------------- launch ----------------
extern "C" void kernel_launch(void* const* d_in, const int* in_sizes, int n_in,
                              void* d_out, int out_size, void* d_ws, size_t ws_size,
                              hipStream_t stream) {
  const float* x = (const float*)d_in[0];
  const float* kqv_w = (const float*)d_in[1];
  const float* kqv_b = (const float*)d_in[2];
  const float* proj_w = (const float*)d_in[3];
  const float* proj_b = (const float*)d_in[4];
  const float* ln1_g = (const float*)d_in[5];
  const float* ln1_b = (const float*)d_in[6];
  const float* ln2_g = (const float*)d_in[7];
  const float* ln2_b = (const float*)d_in[8];
  const float* fc1_w = (const float*)d_in[9];
  const float* fc1_b = (const float*)d_in[10];
  const float* fc2_w = (const float*)d_in[11];
  const float* fc2_b = (const float*)d_in[12];
  float* out = (float*)d_out;

  char* ws = (char*)d_ws;
  size_t off = 0;
  auto alloc = [&](size_t bytes) {
    char* p = ws + off;
    off += (bytes + 255) & ~(size_t)255;
    return p;
  };
  unsigned short* wk = (unsigned short*)alloc((size_t)3072 * 1024 * 2);
  unsigned short* wp = (unsigned short*)alloc((size_t)1024 * 1024 * 2);
  unsigned short* w1 = (unsigned short*)alloc((size_t)4096 * 1024 * 2);
  unsigned short* w2 = (unsigned short*)alloc((size_t)4096 * 1024 * 2);
  unsigned short* hbuf = (unsigned short*)alloc((size_t)8192 * 1024 * 2);  // LN1 out, reused for LN2 out
  unsigned short* kqvb = (unsigned short*)alloc((size_t)8192 * 3072 * 2);
  unsigned short* yb = (unsigned short*)alloc((size_t)8192 * 1024 * 2);
  float* x1 = (float*)alloc((size_t)8192 * 1024 * 4);
  unsigned short* a1 = (unsigned short*)alloc((size_t)8192 * 4096 * 2);

  // cast weights to bf16
  cast_kernel<<<dim3(3072 * 1024 / 1024), 256, 0, stream>>>(kqv_w, wk, 3072 * 1024);
  cast_kernel<<<dim3(1024 * 1024 / 1024), 256, 0, stream>>>(proj_w, wp, 1024 * 1024);
  cast_kernel<<<dim3(4096 * 1024 / 1024), 256, 0, stream>>>(fc1_w, w1, 4096 * 1024);
  cast_kernel<<<dim3(4096 * 1024 / 1024), 256, 0, stream>>>(fc2_w, w2, 4096 * 1024);

  // LN1 -> h (bf16)
  ln_kernel<<<dim3(8192), 256, 0, stream>>>(x, ln1_g, ln1_b, hbuf);

  // kqv = h @ kqv_w^T + b   [8192 x 3072]
  gemm_bt<0><<<dim3(3072 / 128, 8192 / 128), 256, 0, stream>>>(
      hbuf, wk, kqv_b, nullptr, kqvb, nullptr, 8192, 3072, 1024);

  // attention -> y (bf16)
  attn_kernel<<<dim3(16, 128), 256, 0, stream>>>(kqvb, yb);

  // x1 = x + y @ proj_w^T + b   (fp32)
  gemm_bt<1><<<dim3(1024 / 128, 8192 / 128), 256, 0, stream>>>(
      yb, wp, proj_b, x, nullptr, x1, 8192, 1024, 1024);

  // LN2 -> h (bf16, reuse)
  ln_kernel<<<dim3(8192), 256, 0, stream>>>(x1, ln2_g, ln2_b, hbuf);

  // a1 = gelu(h @ fc1_w^T + b)  [8192 x 4096] bf16
  gemm_bt<2><<<dim3(4096 / 128, 8192 / 128), 256, 0, stream>>>(
      hbuf, w1, fc1_b, nullptr, a1, nullptr, 8192, 4096, 1024);

  // out = x1 + a1 @ fc2_w^T + b  (fp32)
  gemm_bt<1><<<dim3(1024 / 128, 8192 / 128), 256, 0, stream>>>(
      a1, w2, fc2_b, x1, nullptr, out, 8192, 1024, 4096);
}